// Round 16
// baseline (62.477 us; speedup 1.0000x reference)
//
#include <hip/hip_runtime.h>
#include <hip/hip_bf16.h>

// Problem: B=32, L=256, K=8, E=768, V=50000 ; M = B*L = 8192
// inputs: hidden [M,E] f32, similar_words [M,K] int32, word2vec [V,E] f32, weight [E,E] f32
// out:    [M,E] f32
//
// r14 model (from r9 subtraction + r5-r13 neutrality): split~3us, gemm~5us,
// attn~52us -> ATTN IS THE BOTTLENECK (latency/occupancy-bound gather).
// Change: online-softmax attn (flash-style running max/denom, rows never
// stored) -> ~60 VGPR instead of ~130 -> ~2x waves/CU, single gather pass,
// normal stores. split_all / gemm (128x192, r13) unchanged.

typedef __attribute__((ext_vector_type(8))) _Float16 f16x8;   // 8 f16 = 4 VGPRs
typedef __attribute__((ext_vector_type(4))) float f32x4;

__device__ __forceinline__ unsigned short f2h(float f) {   // RNE f32 -> f16
    _Float16 h = (_Float16)f;
    return __builtin_bit_cast(unsigned short, h);
}
__device__ __forceinline__ float h2f(unsigned short u) {
    return (float)__builtin_bit_cast(_Float16, u);
}

// async global->LDS, 16B per lane; LDS dest = wave-uniform base + lane*16.
__device__ __forceinline__ void gload16(const void* g, void* l) {
    __builtin_amdgcn_global_load_lds(
        (const __attribute__((address_space(1))) unsigned int*)g,
        (__attribute__((address_space(3))) unsigned int*)l, 16, 0, 0);
}

// ---------------- fused conversion pre-pass (r6 exact) ----------------
__global__ __launch_bounds__(256) void split_all(const float4* __restrict__ x,
                                                 ushort4* __restrict__ hf, int n4,
                                                 const float* __restrict__ W,
                                                 unsigned short* __restrict__ WfT,
                                                 int K, int N, int ablocks) {
    __shared__ float tile[32][33];
    if ((int)blockIdx.x < ablocks) {
        int i = blockIdx.x * 256 + threadIdx.x;
        const int stride = ablocks * 256;
        for (; i < n4; i += stride) {
            float4 v = x[i];
            ushort4 h;
            h.x = f2h(v.x); h.y = f2h(v.y); h.z = f2h(v.z); h.w = f2h(v.w);
            hf[i] = h;
        }
    } else {
        const int bid = blockIdx.x - ablocks;
        const int nbk = K / 32;
        const int bk = (bid % nbk) * 32, bn = (bid / nbk) * 32;
        const int tx = threadIdx.x & 31, ty = threadIdx.x >> 5;
#pragma unroll
        for (int r = ty; r < 32; r += 8)
            tile[r][tx] = W[(size_t)(bk + r) * N + bn + tx];
        __syncthreads();
#pragma unroll
        for (int r = ty; r < 32; r += 8) {
            float v = tile[tx][r];                 // = W[bk+tx][bn+r]
            WfT[(size_t)(bn + r) * K + bk + tx] = f2h(v);
        }
    }
}

// ---------------- f16 MFMA GEMM: 128x192 tile, 1 block/CU (r13 exact) ----------------
#define BM 128
#define BN 192
#define BK 64
#define GEMM_K 768
#define GEMM_N 768

__global__ __launch_bounds__(512, 2) void gemm_mfma_f16(
        const unsigned short* __restrict__ Af, const unsigned short* __restrict__ BfT,
        unsigned short* __restrict__ C) {

    // XCD-aware swizzle (nwg=256, %8==0): 4 n-tiles sharing an A-panel -> one XCD L2.
    const int l   = (blockIdx.x & 7) * 32 + (blockIdx.x >> 3);
    const int bm  = (l >> 2) * BM;               // 64 m-tiles
    const int bn  = (l & 3) * BN;                // 4 n-tiles

    __shared__ unsigned short lds[2 * 2560 * 8];   // 80 KiB: 2 buffers
    const int BOFF = 1024;                          // B region within a buffer (slots)
    const int BUF  = 2560;                          // buffer stride (slots)

    const int tid  = threadIdx.x;
    const int lane = tid & 63;
    const int w    = tid >> 6;                  // wave 0..7
    const int lr   = lane & 15, lg = lane >> 4;
    const int wm   = w >> 2, wn = w & 3;        // 2 x 4 wave grid (64 rows x 48 cols)

    const int lane8 = lane >> 3;                // 0..7
    const int kcl   = (lane & 7) ^ lane8;       // staging: this lane's kc (pre-swizzle)

    f32x4 acc[4][3];
#pragma unroll
    for (int m = 0; m < 4; ++m)
#pragma unroll
        for (int n = 0; n < 3; ++n) acc[m][n] = (f32x4){0.f, 0.f, 0.f, 0.f};

    const unsigned short* aB[2];
    const unsigned short* bB[3];
#pragma unroll
    for (int i = 0; i < 2; ++i)      // A rows: 16 per wave (128 rows / 8 waves)
        aB[i] = Af + (size_t)(bm + 16 * w + 8 * i + lane8) * GEMM_K + kcl * 8;
#pragma unroll
    for (int i = 0; i < 3; ++i)      // B rows (=N cols): 24 per wave (192 / 8)
        bB[i] = BfT + (size_t)(bn + 24 * w + 8 * i + lane8) * GEMM_K + kcl * 8;

    auto STAGE = [&](int k0, int buf) {
#pragma unroll
        for (int i = 0; i < 2; ++i)
            gload16(aB[i] + k0, &lds[(size_t)(buf * BUF + 128 * w + 64 * i) * 8]);
#pragma unroll
        for (int i = 0; i < 3; ++i)
            gload16(bB[i] + k0, &lds[(size_t)(buf * BUF + BOFF + 192 * w + 64 * i) * 8]);
    };

    STAGE(0, 0);
    __syncthreads();                             // drain: buf0 ready

#pragma unroll
    for (int it = 0; it < GEMM_K / BK; ++it) {   // 12 iters, FULLY unrolled
        const int cur = it & 1;
        if (it + 1 < GEMM_K / BK) STAGE((it + 1) * BK, cur ^ 1);   // issue-early

        const int base = cur * BUF;
#pragma unroll
        for (int ks = 0; ks < 2; ++ks) {
            const int kc = ks * 4 + lg;
            const int kx = kc ^ (lr & 7);       // row&7 == lr&7 for all frag rows
            f16x8 a[4], b[3];
#pragma unroll
            for (int m = 0; m < 4; ++m) {
                int slot = base + (wm * 64 + m * 16 + lr) * 8 + kx;
                a[m] = *(const f16x8*)&lds[(size_t)slot * 8];
            }
#pragma unroll
            for (int n = 0; n < 3; ++n) {
                int slot = base + BOFF + (wn * 48 + n * 16 + lr) * 8 + kx;
                b[n] = *(const f16x8*)&lds[(size_t)slot * 8];
            }
#pragma unroll
            for (int m = 0; m < 4; ++m)
#pragma unroll
                for (int n = 0; n < 3; ++n)
                    acc[m][n] = __builtin_amdgcn_mfma_f32_16x16x32_f16(a[m], b[n], acc[m][n], 0, 0, 0);
        }
        __syncthreads();    // drains stage loads (vmcnt 0) + all waves done reading cur
    }

    // Epilogue: C/D layout col=lane&15, row=(lane>>4)*4+reg  [m89/m91]; store f16.
#pragma unroll
    for (int m = 0; m < 4; ++m)
#pragma unroll
        for (int n = 0; n < 3; ++n) {
            const int col = bn + wn * 48 + n * 16 + lr;
            const int r0  = bm + wm * 64 + m * 16 + lg * 4;
#pragma unroll
            for (int j = 0; j < 4; ++j)
                C[(size_t)(r0 + j) * GEMM_N + col] = f2h(acc[m][n][j]);
        }
}

// ---------------- online-softmax gather attention (low-VGPR) ----------------
// Flash-style: running max m, denom l; o rescaled per row; gathered rows are
// never stored. VGPR ~60 -> ~2x occupancy vs ks-in-regs. One gather pass.
__global__ __launch_bounds__(256) void attn_online(
        const unsigned short* __restrict__ qf,
        const int* __restrict__ sws,
        const float* __restrict__ w2v,
        float* __restrict__ out) {
    const int wave = threadIdx.x >> 6;
    const int lane = threadIdx.x & 63;
    const size_t row = (size_t)blockIdx.x * 4 + wave;

    const int4 ia = *(const int4*)(sws + row * 8);
    const int4 ib = *(const int4*)(sws + row * 8 + 4);
    const int id[8] = {ia.x, ia.y, ia.z, ia.w, ib.x, ib.y, ib.z, ib.w};

    const ushort4* q4 = (const ushort4*)(qf + row * 768);
    float4 q[3];
#pragma unroll
    for (int j = 0; j < 3; ++j) {
        ushort4 h = q4[j * 64 + lane];
        q[j].x = h2f(h.x); q[j].y = h2f(h.y); q[j].z = h2f(h.z); q[j].w = h2f(h.w);
    }

    float m = -3.0e38f, l = 0.f;
    float4 o[3];
#pragma unroll
    for (int j = 0; j < 3; ++j) { o[j].x = 0.f; o[j].y = 0.f; o[j].z = 0.f; o[j].w = 0.f; }

#pragma unroll
    for (int k = 0; k < 8; ++k) {
        const float4* kp = (const float4*)(w2v + (size_t)id[k] * 768);
        float4 v[3];
#pragma unroll
        for (int j = 0; j < 3; ++j) v[j] = kp[j * 64 + lane];

        float d = 0.f;
#pragma unroll
        for (int j = 0; j < 3; ++j) {
            d += q[j].x * v[j].x;
            d += q[j].y * v[j].y;
            d += q[j].z * v[j].z;
            d += q[j].w * v[j].w;
        }
#pragma unroll
        for (int s = 1; s < 64; s <<= 1) d += __shfl_xor(d, s);

        // online softmax update (exp(-3e38 - d) flushes to 0 on first iter)
        const float mn = fmaxf(m, d);
        const float sc = __expf(m - mn);
        const float p  = __expf(d - mn);
        l = l * sc + p;
#pragma unroll
        for (int j = 0; j < 3; ++j) {
            o[j].x = o[j].x * sc + p * v[j].x;
            o[j].y = o[j].y * sc + p * v[j].y;
            o[j].z = o[j].z * sc + p * v[j].z;
            o[j].w = o[j].w * sc + p * v[j].w;
        }
        m = mn;
    }

    const float inv = 1.f / l;
    float4* o4 = (float4*)(out + row * 768);
#pragma unroll
    for (int j = 0; j < 3; ++j) {
        float4 r;
        r.x = o[j].x * inv; r.y = o[j].y * inv; r.z = o[j].z * inv; r.w = o[j].w * inv;
        o4[j * 64 + lane] = r;
    }
}

// ---------------- fallback f32 path (if ws too small or M != 8192) ----------------
#define GM_BM 128
#define GM_BN 64
#define GM_BK 16
#define GM_TM 8
#define GM_TN 4

__global__ __launch_bounds__(256) void gemm_qproj(const float* __restrict__ A,
                                                  const float* __restrict__ B,
                                                  float* __restrict__ C,
                                                  int M, int N, int K) {
    __shared__ float As[GM_BK][GM_BM];
    __shared__ float Bs[GM_BK][GM_BN];
    const int tid = threadIdx.x;
    const int tx = tid & 15;
    const int ty = tid >> 4;
    const int bm = blockIdx.x * GM_BM;
    const int bn = blockIdx.y * GM_BN;
    float acc[GM_TM][GM_TN];
#pragma unroll
    for (int i = 0; i < GM_TM; ++i)
#pragma unroll
        for (int j = 0; j < GM_TN; ++j) acc[i][j] = 0.f;
    for (int k0 = 0; k0 < K; k0 += GM_BK) {
#pragma unroll
        for (int i = 0; i < 2; ++i) {
            int idx = tid * 2 + i;
            int row = idx >> 2;
            int c4  = idx & 3;
            float4 v = *(const float4*)(A + (size_t)(bm + row) * K + k0 + c4 * 4);
            As[c4 * 4 + 0][row] = v.x;
            As[c4 * 4 + 1][row] = v.y;
            As[c4 * 4 + 2][row] = v.z;
            As[c4 * 4 + 3][row] = v.w;
        }
        {
            int row = tid >> 4;
            int c4  = tid & 15;
            float4 v = *(const float4*)(B + (size_t)(k0 + row) * N + bn + c4 * 4);
            *(float4*)&Bs[row][c4 * 4] = v;
        }
        __syncthreads();
#pragma unroll
        for (int k = 0; k < GM_BK; ++k) {
            float a[GM_TM], b[GM_TN];
#pragma unroll
            for (int i = 0; i < GM_TM; ++i) a[i] = As[k][ty * GM_TM + i];
#pragma unroll
            for (int j = 0; j < GM_TN; ++j) b[j] = Bs[k][tx * GM_TN + j];
#pragma unroll
            for (int i = 0; i < GM_TM; ++i)
#pragma unroll
                for (int j = 0; j < GM_TN; ++j) acc[i][j] += a[i] * b[j];
        }
        __syncthreads();
    }
#pragma unroll
    for (int i = 0; i < GM_TM; ++i) {
        float4 v;
        v.x = acc[i][0]; v.y = acc[i][1]; v.z = acc[i][2]; v.w = acc[i][3];
        *(float4*)(C + (size_t)(bm + ty * GM_TM + i) * N + bn + tx * GM_TN) = v;
    }
}

__global__ __launch_bounds__(256) void attn_fused(const float* __restrict__ qproj,
                                                  const int* __restrict__ sws,
                                                  const float* __restrict__ w2v,
                                                  float* __restrict__ out) {
    const int wave = threadIdx.x >> 6;
    const int lane = threadIdx.x & 63;
    const size_t row = (size_t)blockIdx.x * 4 + wave;

    const float4* q4 = (const float4*)(qproj + row * 768);
    float4 q[3];
#pragma unroll
    for (int j = 0; j < 3; ++j) q[j] = q4[j * 64 + lane];

    float4 ks[8][3];
    float dot[8];
#pragma unroll
    for (int k = 0; k < 8; ++k) {
        int id = sws[row * 8 + k];
        const float4* kp = (const float4*)(w2v + (size_t)id * 768);
        float d = 0.f;
#pragma unroll
        for (int j = 0; j < 3; ++j) {
            float4 v = kp[j * 64 + lane];
            ks[k][j] = v;
            d += q[j].x * v.x + q[j].y * v.y + q[j].z * v.z + q[j].w * v.w;
        }
        dot[k] = d;
    }
#pragma unroll
    for (int k = 0; k < 8; ++k) {
        float d = dot[k];
#pragma unroll
        for (int m = 1; m < 64; m <<= 1) d += __shfl_xor(d, m);
        dot[k] = d;
    }
    float mx = dot[0];
#pragma unroll
    for (int k = 1; k < 8; ++k) mx = fmaxf(mx, dot[k]);
    float wq[8];
    float s = 0.f;
#pragma unroll
    for (int k = 0; k < 8; ++k) { wq[k] = __expf(dot[k] - mx); s += wq[k]; }
    const float inv = 1.f / s;

    float4 o[3];
#pragma unroll
    for (int j = 0; j < 3; ++j) { o[j].x = 0.f; o[j].y = 0.f; o[j].z = 0.f; o[j].w = 0.f; }
#pragma unroll
    for (int k = 0; k < 8; ++k) {
        const float a = wq[k] * inv;
#pragma unroll
        for (int j = 0; j < 3; ++j) {
            o[j].x += a * ks[k][j].x;
            o[j].y += a * ks[k][j].y;
            o[j].z += a * ks[k][j].z;
            o[j].w += a * ks[k][j].w;
        }
    }
    float4* o4 = (float4*)(out + row * 768);
#pragma unroll
    for (int j = 0; j < 3; ++j) o4[j * 64 + lane] = o[j];
}

extern "C" void kernel_launch(void* const* d_in, const int* in_sizes, int n_in,
                              void* d_out, int out_size, void* d_ws, size_t ws_size,
                              hipStream_t stream) {
    const float* hidden = (const float*)d_in[0];
    const int*   sws    = (const int*)d_in[1];
    const float* w2v    = (const float*)d_in[2];
    const float* weight = (const float*)d_in[3];
    float*       out    = (float*)d_out;

    const int E = 768;
    const int M = in_sizes[0] / E;            // 8192

    const size_t szA = (size_t)M * E;          // elements
    const size_t szB = (size_t)E * E;
    const size_t need = (2 * szA + szB) * sizeof(unsigned short);   // Af + Qf + WfT

    if (ws_size >= need && M == 8192) {
        unsigned short* Af  = (unsigned short*)d_ws;
        unsigned short* WfT = Af + szA;
        unsigned short* Qf  = WfT + szB;

        const int ablocks = 2048;
        const int wblocks = (E / 32) * (E / 32);   // 576
        split_all<<<ablocks + wblocks, 256, 0, stream>>>(
            (const float4*)hidden, (ushort4*)Af, M * E / 4,
            weight, WfT, E, E, ablocks);

        dim3 ggrid((M / BM) * (E / BN));      // 64*4 = 256 blocks, %8==0, 1/CU
        gemm_mfma_f16<<<ggrid, 512, 0, stream>>>(Af, WfT, Qf);

        attn_online<<<dim3(M / 4), 256, 0, stream>>>(Qf, sws, w2v, out);
    } else {
        float* qproj = out;                   // staged through d_out
        dim3 ggrid(M / GM_BM, E / GM_BN);
        gemm_qproj<<<ggrid, 256, 0, stream>>>(hidden, weight, qproj, M, E, E);
        attn_fused<<<dim3(M / 4), 256, 0, stream>>>(qproj, sws, w2v, out);
    }
}

// Round 17
// 61.061 us; speedup vs baseline: 1.0232x; 1.0232x over previous
//
#include <hip/hip_runtime.h>
#include <hip/hip_bf16.h>

// Problem: B=32, L=256, K=8, E=768, V=50000 ; M = B*L = 8192
// inputs: hidden [M,E] f32, similar_words [M,K] int32, word2vec [V,E] f32, weight [E,E] f32
// out:    [M,E] f32
//
// r14 model (from r9 subtraction + r5-r13 neutrality): split~3us, gemm~5us,
// attn~52us -> ATTN IS THE BOTTLENECK (latency/occupancy-bound gather).
// Change: online-softmax attn (flash-style running max/denom, rows never
// stored) -> ~60 VGPR instead of ~130 -> ~2x waves/CU, single gather pass,
// normal stores. split_all / gemm (128x192, r13) unchanged.

typedef __attribute__((ext_vector_type(8))) _Float16 f16x8;   // 8 f16 = 4 VGPRs
typedef __attribute__((ext_vector_type(4))) float f32x4;

__device__ __forceinline__ unsigned short f2h(float f) {   // RNE f32 -> f16
    _Float16 h = (_Float16)f;
    return __builtin_bit_cast(unsigned short, h);
}
__device__ __forceinline__ float h2f(unsigned short u) {
    return (float)__builtin_bit_cast(_Float16, u);
}

// async global->LDS, 16B per lane; LDS dest = wave-uniform base + lane*16.
__device__ __forceinline__ void gload16(const void* g, void* l) {
    __builtin_amdgcn_global_load_lds(
        (const __attribute__((address_space(1))) unsigned int*)g,
        (__attribute__((address_space(3))) unsigned int*)l, 16, 0, 0);
}

// ---------------- fused conversion pre-pass (r6 exact) ----------------
__global__ __launch_bounds__(256) void split_all(const float4* __restrict__ x,
                                                 ushort4* __restrict__ hf, int n4,
                                                 const float* __restrict__ W,
                                                 unsigned short* __restrict__ WfT,
                                                 int K, int N, int ablocks) {
    __shared__ float tile[32][33];
    if ((int)blockIdx.x < ablocks) {
        int i = blockIdx.x * 256 + threadIdx.x;
        const int stride = ablocks * 256;
        for (; i < n4; i += stride) {
            float4 v = x[i];
            ushort4 h;
            h.x = f2h(v.x); h.y = f2h(v.y); h.z = f2h(v.z); h.w = f2h(v.w);
            hf[i] = h;
        }
    } else {
        const int bid = blockIdx.x - ablocks;
        const int nbk = K / 32;
        const int bk = (bid % nbk) * 32, bn = (bid / nbk) * 32;
        const int tx = threadIdx.x & 31, ty = threadIdx.x >> 5;
#pragma unroll
        for (int r = ty; r < 32; r += 8)
            tile[r][tx] = W[(size_t)(bk + r) * N + bn + tx];
        __syncthreads();
#pragma unroll
        for (int r = ty; r < 32; r += 8) {
            float v = tile[tx][r];                 // = W[bk+tx][bn+r]
            WfT[(size_t)(bn + r) * K + bk + tx] = f2h(v);
        }
    }
}

// ---------------- f16 MFMA GEMM: 128x192 tile, 1 block/CU (r13 exact) ----------------
#define BM 128
#define BN 192
#define BK 64
#define GEMM_K 768
#define GEMM_N 768

__global__ __launch_bounds__(512, 2) void gemm_mfma_f16(
        const unsigned short* __restrict__ Af, const unsigned short* __restrict__ BfT,
        unsigned short* __restrict__ C) {

    // XCD-aware swizzle (nwg=256, %8==0): 4 n-tiles sharing an A-panel -> one XCD L2.
    const int l   = (blockIdx.x & 7) * 32 + (blockIdx.x >> 3);
    const int bm  = (l >> 2) * BM;               // 64 m-tiles
    const int bn  = (l & 3) * BN;                // 4 n-tiles

    __shared__ unsigned short lds[2 * 2560 * 8];   // 80 KiB: 2 buffers
    const int BOFF = 1024;                          // B region within a buffer (slots)
    const int BUF  = 2560;                          // buffer stride (slots)

    const int tid  = threadIdx.x;
    const int lane = tid & 63;
    const int w    = tid >> 6;                  // wave 0..7
    const int lr   = lane & 15, lg = lane >> 4;
    const int wm   = w >> 2, wn = w & 3;        // 2 x 4 wave grid (64 rows x 48 cols)

    const int lane8 = lane >> 3;                // 0..7
    const int kcl   = (lane & 7) ^ lane8;       // staging: this lane's kc (pre-swizzle)

    f32x4 acc[4][3];
#pragma unroll
    for (int m = 0; m < 4; ++m)
#pragma unroll
        for (int n = 0; n < 3; ++n) acc[m][n] = (f32x4){0.f, 0.f, 0.f, 0.f};

    const unsigned short* aB[2];
    const unsigned short* bB[3];
#pragma unroll
    for (int i = 0; i < 2; ++i)      // A rows: 16 per wave (128 rows / 8 waves)
        aB[i] = Af + (size_t)(bm + 16 * w + 8 * i + lane8) * GEMM_K + kcl * 8;
#pragma unroll
    for (int i = 0; i < 3; ++i)      // B rows (=N cols): 24 per wave (192 / 8)
        bB[i] = BfT + (size_t)(bn + 24 * w + 8 * i + lane8) * GEMM_K + kcl * 8;

    auto STAGE = [&](int k0, int buf) {
#pragma unroll
        for (int i = 0; i < 2; ++i)
            gload16(aB[i] + k0, &lds[(size_t)(buf * BUF + 128 * w + 64 * i) * 8]);
#pragma unroll
        for (int i = 0; i < 3; ++i)
            gload16(bB[i] + k0, &lds[(size_t)(buf * BUF + BOFF + 192 * w + 64 * i) * 8]);
    };

    STAGE(0, 0);
    __syncthreads();                             // drain: buf0 ready

#pragma unroll
    for (int it = 0; it < GEMM_K / BK; ++it) {   // 12 iters, FULLY unrolled
        const int cur = it & 1;
        if (it + 1 < GEMM_K / BK) STAGE((it + 1) * BK, cur ^ 1);   // issue-early

        const int base = cur * BUF;
#pragma unroll
        for (int ks = 0; ks < 2; ++ks) {
            const int kc = ks * 4 + lg;
            const int kx = kc ^ (lr & 7);       // row&7 == lr&7 for all frag rows
            f16x8 a[4], b[3];
#pragma unroll
            for (int m = 0; m < 4; ++m) {
                int slot = base + (wm * 64 + m * 16 + lr) * 8 + kx;
                a[m] = *(const f16x8*)&lds[(size_t)slot * 8];
            }
#pragma unroll
            for (int n = 0; n < 3; ++n) {
                int slot = base + BOFF + (wn * 48 + n * 16 + lr) * 8 + kx;
                b[n] = *(const f16x8*)&lds[(size_t)slot * 8];
            }
#pragma unroll
            for (int m = 0; m < 4; ++m)
#pragma unroll
                for (int n = 0; n < 3; ++n)
                    acc[m][n] = __builtin_amdgcn_mfma_f32_16x16x32_f16(a[m], b[n], acc[m][n], 0, 0, 0);
        }
        __syncthreads();    // drains stage loads (vmcnt 0) + all waves done reading cur
    }

    // Epilogue: C/D layout col=lane&15, row=(lane>>4)*4+reg  [m89/m91]; store f16.
#pragma unroll
    for (int m = 0; m < 4; ++m)
#pragma unroll
        for (int n = 0; n < 3; ++n) {
            const int col = bn + wn * 48 + n * 16 + lr;
            const int r0  = bm + wm * 64 + m * 16 + lg * 4;
#pragma unroll
            for (int j = 0; j < 4; ++j)
                C[(size_t)(r0 + j) * GEMM_N + col] = f2h(acc[m][n][j]);
        }
}

// ---------------- online-softmax gather attention (low-VGPR) ----------------
// Flash-style: running max m, denom l; o rescaled per row; gathered rows are
// never stored. VGPR ~60 -> ~2x occupancy vs ks-in-regs. One gather pass.
__global__ __launch_bounds__(256) void attn_online(
        const unsigned short* __restrict__ qf,
        const int* __restrict__ sws,
        const float* __restrict__ w2v,
        float* __restrict__ out) {
    const int wave = threadIdx.x >> 6;
    const int lane = threadIdx.x & 63;
    const size_t row = (size_t)blockIdx.x * 4 + wave;

    const int4 ia = *(const int4*)(sws + row * 8);
    const int4 ib = *(const int4*)(sws + row * 8 + 4);
    const int id[8] = {ia.x, ia.y, ia.z, ia.w, ib.x, ib.y, ib.z, ib.w};

    const ushort4* q4 = (const ushort4*)(qf + row * 768);
    float4 q[3];
#pragma unroll
    for (int j = 0; j < 3; ++j) {
        ushort4 h = q4[j * 64 + lane];
        q[j].x = h2f(h.x); q[j].y = h2f(h.y); q[j].z = h2f(h.z); q[j].w = h2f(h.w);
    }

    float m = -3.0e38f, l = 0.f;
    float4 o[3];
#pragma unroll
    for (int j = 0; j < 3; ++j) { o[j].x = 0.f; o[j].y = 0.f; o[j].z = 0.f; o[j].w = 0.f; }

#pragma unroll
    for (int k = 0; k < 8; ++k) {
        const float4* kp = (const float4*)(w2v + (size_t)id[k] * 768);
        float4 v[3];
#pragma unroll
        for (int j = 0; j < 3; ++j) v[j] = kp[j * 64 + lane];

        float d = 0.f;
#pragma unroll
        for (int j = 0; j < 3; ++j) {
            d += q[j].x * v[j].x;
            d += q[j].y * v[j].y;
            d += q[j].z * v[j].z;
            d += q[j].w * v[j].w;
        }
#pragma unroll
        for (int s = 1; s < 64; s <<= 1) d += __shfl_xor(d, s);

        // online softmax update (exp(-3e38 - d) flushes to 0 on first iter)
        const float mn = fmaxf(m, d);
        const float sc = __expf(m - mn);
        const float p  = __expf(d - mn);
        l = l * sc + p;
#pragma unroll
        for (int j = 0; j < 3; ++j) {
            o[j].x = o[j].x * sc + p * v[j].x;
            o[j].y = o[j].y * sc + p * v[j].y;
            o[j].z = o[j].z * sc + p * v[j].z;
            o[j].w = o[j].w * sc + p * v[j].w;
        }
        m = mn;
    }

    const float inv = 1.f / l;
    float4* o4 = (float4*)(out + row * 768);
#pragma unroll
    for (int j = 0; j < 3; ++j) {
        float4 r;
        r.x = o[j].x * inv; r.y = o[j].y * inv; r.z = o[j].z * inv; r.w = o[j].w * inv;
        o4[j * 64 + lane] = r;
    }
}

// ---------------- fallback f32 path (if ws too small or M != 8192) ----------------
#define GM_BM 128
#define GM_BN 64
#define GM_BK 16
#define GM_TM 8
#define GM_TN 4

__global__ __launch_bounds__(256) void gemm_qproj(const float* __restrict__ A,
                                                  const float* __restrict__ B,
                                                  float* __restrict__ C,
                                                  int M, int N, int K) {
    __shared__ float As[GM_BK][GM_BM];
    __shared__ float Bs[GM_BK][GM_BN];
    const int tid = threadIdx.x;
    const int tx = tid & 15;
    const int ty = tid >> 4;
    const int bm = blockIdx.x * GM_BM;
    const int bn = blockIdx.y * GM_BN;
    float acc[GM_TM][GM_TN];
#pragma unroll
    for (int i = 0; i < GM_TM; ++i)
#pragma unroll
        for (int j = 0; j < GM_TN; ++j) acc[i][j] = 0.f;
    for (int k0 = 0; k0 < K; k0 += GM_BK) {
#pragma unroll
        for (int i = 0; i < 2; ++i) {
            int idx = tid * 2 + i;
            int row = idx >> 2;
            int c4  = idx & 3;
            float4 v = *(const float4*)(A + (size_t)(bm + row) * K + k0 + c4 * 4);
            As[c4 * 4 + 0][row] = v.x;
            As[c4 * 4 + 1][row] = v.y;
            As[c4 * 4 + 2][row] = v.z;
            As[c4 * 4 + 3][row] = v.w;
        }
        {
            int row = tid >> 4;
            int c4  = tid & 15;
            float4 v = *(const float4*)(B + (size_t)(k0 + row) * N + bn + c4 * 4);
            *(float4*)&Bs[row][c4 * 4] = v;
        }
        __syncthreads();
#pragma unroll
        for (int k = 0; k < GM_BK; ++k) {
            float a[GM_TM], b[GM_TN];
#pragma unroll
            for (int i = 0; i < GM_TM; ++i) a[i] = As[k][ty * GM_TM + i];
#pragma unroll
            for (int j = 0; j < GM_TN; ++j) b[j] = Bs[k][tx * GM_TN + j];
#pragma unroll
            for (int i = 0; i < GM_TM; ++i)
#pragma unroll
                for (int j = 0; j < GM_TN; ++j) acc[i][j] += a[i] * b[j];
        }
        __syncthreads();
    }
#pragma unroll
    for (int i = 0; i < GM_TM; ++i) {
        float4 v;
        v.x = acc[i][0]; v.y = acc[i][1]; v.z = acc[i][2]; v.w = acc[i][3];
        *(float4*)(C + (size_t)(bm + ty * GM_TM + i) * N + bn + tx * GM_TN) = v;
    }
}

__global__ __launch_bounds__(256) void attn_fused(const float* __restrict__ qproj,
                                                  const int* __restrict__ sws,
                                                  const float* __restrict__ w2v,
                                                  float* __restrict__ out) {
    const int wave = threadIdx.x >> 6;
    const int lane = threadIdx.x & 63;
    const size_t row = (size_t)blockIdx.x * 4 + wave;

    const float4* q4 = (const float4*)(qproj + row * 768);
    float4 q[3];
#pragma unroll
    for (int j = 0; j < 3; ++j) q[j] = q4[j * 64 + lane];

    float4 ks[8][3];
    float dot[8];
#pragma unroll
    for (int k = 0; k < 8; ++k) {
        int id = sws[row * 8 + k];
        const float4* kp = (const float4*)(w2v + (size_t)id * 768);
        float d = 0.f;
#pragma unroll
        for (int j = 0; j < 3; ++j) {
            float4 v = kp[j * 64 + lane];
            ks[k][j] = v;
            d += q[j].x * v.x + q[j].y * v.y + q[j].z * v.z + q[j].w * v.w;
        }
        dot[k] = d;
    }
#pragma unroll
    for (int k = 0; k < 8; ++k) {
        float d = dot[k];
#pragma unroll
        for (int m = 1; m < 64; m <<= 1) d += __shfl_xor(d, m);
        dot[k] = d;
    }
    float mx = dot[0];
#pragma unroll
    for (int k = 1; k < 8; ++k) mx = fmaxf(mx, dot[k]);
    float wq[8];
    float s = 0.f;
#pragma unroll
    for (int k = 0; k < 8; ++k) { wq[k] = __expf(dot[k] - mx); s += wq[k]; }
    const float inv = 1.f / s;

    float4 o[3];
#pragma unroll
    for (int j = 0; j < 3; ++j) { o[j].x = 0.f; o[j].y = 0.f; o[j].z = 0.f; o[j].w = 0.f; }
#pragma unroll
    for (int k = 0; k < 8; ++k) {
        const float a = wq[k] * inv;
#pragma unroll
        for (int j = 0; j < 3; ++j) {
            o[j].x += a * ks[k][j].x;
            o[j].y += a * ks[k][j].y;
            o[j].z += a * ks[k][j].z;
            o[j].w += a * ks[k][j].w;
        }
    }
    float4* o4 = (float4*)(out + row * 768);
#pragma unroll
    for (int j = 0; j < 3; ++j) o4[j * 64 + lane] = o[j];
}

extern "C" void kernel_launch(void* const* d_in, const int* in_sizes, int n_in,
                              void* d_out, int out_size, void* d_ws, size_t ws_size,
                              hipStream_t stream) {
    const float* hidden = (const float*)d_in[0];
    const int*   sws    = (const int*)d_in[1];
    const float* w2v    = (const float*)d_in[2];
    const float* weight = (const float*)d_in[3];
    float*       out    = (float*)d_out;

    const int E = 768;
    const int M = in_sizes[0] / E;            // 8192

    const size_t szA = (size_t)M * E;          // elements
    const size_t szB = (size_t)E * E;
    const size_t need = (2 * szA + szB) * sizeof(unsigned short);   // Af + Qf + WfT

    if (ws_size >= need && M == 8192) {
        unsigned short* Af  = (unsigned short*)d_ws;
        unsigned short* WfT = Af + szA;
        unsigned short* Qf  = WfT + szB;

        const int ablocks = 2048;
        const int wblocks = (E / 32) * (E / 32);   // 576
        split_all<<<ablocks + wblocks, 256, 0, stream>>>(
            (const float4*)hidden, (ushort4*)Af, M * E / 4,
            weight, WfT, E, E, ablocks);

        dim3 ggrid((M / BM) * (E / BN));      // 64*4 = 256 blocks, %8==0, 1/CU
        gemm_mfma_f16<<<ggrid, 512, 0, stream>>>(Af, WfT, Qf);

        attn_online<<<dim3(M / 4), 256, 0, stream>>>(Qf, sws, w2v, out);
    } else {
        float* qproj = out;                   // staged through d_out
        dim3 ggrid(M / GM_BM, E / GM_BN);
        gemm_qproj<<<ggrid, 256, 0, stream>>>(hidden, weight, qproj, M, E, E);
        attn_fused<<<dim3(M / 4), 256, 0, stream>>>(qproj, sws, w2v, out);
    }
}